// Round 2
// baseline (436.298 us; speedup 1.0000x reference)
//
#include <hip/hip_runtime.h>
#include <cstdint>
#include <cstddef>

// x = x556 + x570 (fp32 [12544,1024]); LayerNorm over C=1024; y = xn @ W^T + b
// (W [4096,1024] fp32, row-major = B^T GEMM layout); out = gelu_erf(y), fp32.
// Internal compute: bf16 MFMA (threshold is bf16-scale: 8*ulp).
#define M_DIM 12544
#define K_DIM 1024
#define N_DIM 4096

typedef __bf16 bf16x8 __attribute__((ext_vector_type(8)));
typedef float f32x4 __attribute__((ext_vector_type(4)));

__device__ __forceinline__ unsigned short bf16_rne(float f) {
    unsigned int u = __float_as_uint(f);
    u += 0x7FFFu + ((u >> 16) & 1u);
    return (unsigned short)(u >> 16);
}
__device__ __forceinline__ unsigned int pack2_bf16(float lo, float hi) {
    return (unsigned int)bf16_rne(lo) | ((unsigned int)bf16_rne(hi) << 16);
}
__device__ __forceinline__ float gelu_erf(float x) {
    return 0.5f * x * (1.0f + erff(x * 0.70710678118654752440f));
}

// async global->LDS, 16B per lane. LDS dest must be wave-uniform base + lane*16.
__device__ __forceinline__ void async_load16(const void* g, void* l) {
    __builtin_amdgcn_global_load_lds(
        (const __attribute__((address_space(1))) void*)g,
        (__attribute__((address_space(3))) void*)l,
        16, 0, 0);
}

// ---------------- residual add + LayerNorm (fp32 in) -> bf16 xn ----------------
// 1 wave per row of 1024; lane handles 4 interleaved float4 chunks (coalesced).
__global__ __launch_bounds__(256) void ln_fused(
    const float* __restrict__ x0,
    const float* __restrict__ x1,
    const float* __restrict__ gam,
    const float* __restrict__ bet,
    unsigned short* __restrict__ o)
{
    const int lane = threadIdx.x & 63;
    const int wv   = threadIdx.x >> 6;
    const size_t row = (size_t)blockIdx.x * 4 + wv;
    const float* p0 = x0 + row * K_DIM;
    const float* p1 = x1 + row * K_DIM;

    float v[16];
    #pragma unroll
    for (int i = 0; i < 4; ++i) {
        float4 a = *(const float4*)(p0 + i * 256 + lane * 4);
        float4 b = *(const float4*)(p1 + i * 256 + lane * 4);
        v[4*i+0] = a.x + b.x; v[4*i+1] = a.y + b.y;
        v[4*i+2] = a.z + b.z; v[4*i+3] = a.w + b.w;
    }

    float s = 0.f, sq = 0.f;
    #pragma unroll
    for (int i = 0; i < 16; ++i) { s += v[i]; sq += v[i] * v[i]; }
    #pragma unroll
    for (int m = 32; m >= 1; m >>= 1) {
        s  += __shfl_xor(s,  m);
        sq += __shfl_xor(sq, m);
    }
    const float mean = s * (1.0f / 1024.0f);
    float var = sq * (1.0f / 1024.0f) - mean * mean;
    var = fmaxf(var, 0.0f);
    const float rstd = rsqrtf(var + 1e-5f);

    unsigned short* po = o + row * K_DIM;
    #pragma unroll
    for (int i = 0; i < 4; ++i) {
        float4 g  = *(const float4*)(gam + i * 256 + lane * 4);
        float4 be = *(const float4*)(bet + i * 256 + lane * 4);
        float y0 = (v[4*i+0] - mean) * rstd * g.x + be.x;
        float y1 = (v[4*i+1] - mean) * rstd * g.y + be.y;
        float y2 = (v[4*i+2] - mean) * rstd * g.z + be.z;
        float y3 = (v[4*i+3] - mean) * rstd * g.w + be.w;
        uint2 r;
        r.x = pack2_bf16(y0, y1);
        r.y = pack2_bf16(y2, y3);
        *(uint2*)(po + i * 256 + lane * 4) = r;
    }
}

// ---------------- W fp32 -> bf16 ----------------
__global__ __launch_bounds__(256) void w_to_bf16(
    const float* __restrict__ w, unsigned short* __restrict__ o)
{
    const size_t i = ((size_t)blockIdx.x * 256 + threadIdx.x) * 4;
    float4 v = *(const float4*)(w + i);
    uint2 r;
    r.x = pack2_bf16(v.x, v.y);
    r.y = pack2_bf16(v.z, v.w);
    *(uint2*)(o + i) = r;
}

// ---------------- GEMM: C[M,N] = gelu(A[M,K] @ B[N,K]^T + bias) ----------------
// m97 structure: 128x128 tile, BK=32, 4 waves, 4x4 16x16x32 MFMA per wave,
// global_load_lds width=16 staging, 2-barrier K-loop. A,B bf16; bias/C fp32.
__global__ __launch_bounds__(256) void gemm_bias_gelu(
    const unsigned short* __restrict__ A,    // xn [M,K] bf16
    const unsigned short* __restrict__ B,    // W  [N,K] bf16
    const float* __restrict__ bias,          // [N] fp32
    float* __restrict__ C)                   // [M,N] fp32
{
    __shared__ __align__(16) unsigned short At[128 * 32];
    __shared__ __align__(16) unsigned short Bt[128 * 32];

    const int t  = threadIdx.x;
    const int bn = blockIdx.x;   // 0..31
    const int bm = blockIdx.y;   // 0..97
    const int m0 = bm * 128, n0 = bn * 128;

    // staging: 512 16B-chunks per tile; thread t handles chunks t and t+256.
    // chunk c -> LDS row c/4, cols (c%4)*8..+8 (bf16).
    const int srow = t >> 2, sseg = t & 3;
    const unsigned short* ag0 = A + (size_t)(m0 + srow) * K_DIM + sseg * 8;
    const unsigned short* ag1 = A + (size_t)(m0 + srow + 64) * K_DIM + sseg * 8;
    const unsigned short* bg0 = B + (size_t)(n0 + srow) * K_DIM + sseg * 8;
    const unsigned short* bg1 = B + (size_t)(n0 + srow + 64) * K_DIM + sseg * 8;
    unsigned short* al0 = &At[t * 8];
    unsigned short* al1 = &At[(t + 256) * 8];
    unsigned short* bl0 = &Bt[t * 8];
    unsigned short* bl1 = &Bt[(t + 256) * 8];

    const int lane = t & 63;
    const int w    = t >> 6;
    const int wm   = (w >> 1) * 64;   // wave m-offset in tile
    const int wn   = (w & 1) * 64;    // wave n-offset in tile
    const int mrow = lane & 15;
    const int quad = lane >> 4;

    f32x4 acc[4][4] = {};

    for (int kb = 0; kb < K_DIM / 32; ++kb) {
        __syncthreads();   // prior compute done before overwrite
        async_load16(ag0, al0);
        async_load16(ag1, al1);
        async_load16(bg0, bl0);
        async_load16(bg1, bl1);
        ag0 += 32; ag1 += 32; bg0 += 32; bg1 += 32;
        __syncthreads();   // staging complete (compiler drains vmcnt)

        bf16x8 af[4], bfr[4];
        #pragma unroll
        for (int i = 0; i < 4; ++i)
            af[i] = *(const bf16x8*)&At[(wm + i * 16 + mrow) * 32 + quad * 8];
        #pragma unroll
        for (int j = 0; j < 4; ++j)
            bfr[j] = *(const bf16x8*)&Bt[(wn + j * 16 + mrow) * 32 + quad * 8];

        #pragma unroll
        for (int i = 0; i < 4; ++i)
            #pragma unroll
            for (int j = 0; j < 4; ++j)
                acc[i][j] = __builtin_amdgcn_mfma_f32_16x16x32_bf16(af[i], bfr[j], acc[i][j], 0, 0, 0);
    }

    // epilogue: C/D layout col=lane&15, row=quad*4+r
    #pragma unroll
    for (int j = 0; j < 4; ++j) {
        const int n = n0 + wn + j * 16 + mrow;
        const float bj = bias[n];
        #pragma unroll
        for (int i = 0; i < 4; ++i) {
            const int mbase = m0 + wm + i * 16 + quad * 4;
            #pragma unroll
            for (int r = 0; r < 4; ++r) {
                float vv = acc[i][j][r] + bj;
                C[(size_t)(mbase + r) * N_DIM + n] = gelu_erf(vv);
            }
        }
    }
}

extern "C" void kernel_launch(void* const* d_in, const int* in_sizes, int n_in,
                              void* d_out, int out_size, void* d_ws, size_t ws_size,
                              hipStream_t stream) {
    const float* x556 = (const float*)d_in[0];
    const float* x570 = (const float*)d_in[1];
    const float* gam  = (const float*)d_in[2];
    const float* bet  = (const float*)d_in[3];
    const float* Wlin = (const float*)d_in[4];
    const float* blin = (const float*)d_in[5];
    float* out = (float*)d_out;

    // ws layout: xn bf16 [12544*1024] = 25.69 MB, then Wb bf16 [4096*1024] = 8.39 MB
    unsigned short* xn = (unsigned short*)d_ws;
    unsigned short* wb = xn + (size_t)M_DIM * K_DIM;

    ln_fused<<<M_DIM / 4, 256, 0, stream>>>(x556, x570, gam, bet, xn);
    w_to_bf16<<<(N_DIM * K_DIM / 4) / 256, 256, 0, stream>>>(Wlin, wb);
    gemm_bias_gelu<<<dim3(N_DIM / 128, M_DIM / 128), 256, 0, stream>>>(xn, wb, blin, out);
}

// Round 3
// 420.354 us; speedup vs baseline: 1.0379x; 1.0379x over previous
//
#include <hip/hip_runtime.h>
#include <cstdint>
#include <cstddef>

// x = x556 + x570 (fp32 [12544,1024]); LayerNorm over C=1024; y = xn @ W^T + b
// (W [4096,1024] fp32, row-major = B^T GEMM layout); out = gelu(y), fp32.
// Internal compute: bf16 MFMA 32x32x16; tanh-form GELU (|err| vs erf ~1e-3 << 6.4e-2 thr).
#define M_DIM 12544
#define K_DIM 1024
#define N_DIM 4096

typedef __bf16 bf16x8 __attribute__((ext_vector_type(8)));
typedef float f32x16 __attribute__((ext_vector_type(16)));

__device__ __forceinline__ unsigned short bf16_rne(float f) {
    unsigned int u = __float_as_uint(f);
    u += 0x7FFFu + ((u >> 16) & 1u);
    return (unsigned short)(u >> 16);
}
__device__ __forceinline__ unsigned int pack2_bf16(float lo, float hi) {
    return (unsigned int)bf16_rne(lo) | ((unsigned int)bf16_rne(hi) << 16);
}
// tanh-form GELU: x * sigmoid(1.5957691*x*(1+0.044715 x^2)); ~8 VALU ops vs erff's ~25.
__device__ __forceinline__ float gelu_fast(float x) {
    float t = 1.5957691216057308f * x * fmaf(0.044715f, x * x, 1.0f);
    float e = __expf(-t);                       // v_exp_f32
    return x * __builtin_amdgcn_rcpf(1.0f + e); // v_rcp_f32
}

// async global->LDS, 16B per lane. LDS dest must be wave-uniform base + lane*16.
__device__ __forceinline__ void async_load16(const void* g, void* l) {
    __builtin_amdgcn_global_load_lds(
        (const __attribute__((address_space(1))) void*)g,
        (__attribute__((address_space(3))) void*)l,
        16, 0, 0);
}

// ---------------- residual add + LayerNorm (fp32 in) -> bf16 xn ----------------
__global__ __launch_bounds__(256) void ln_fused(
    const float* __restrict__ x0,
    const float* __restrict__ x1,
    const float* __restrict__ gam,
    const float* __restrict__ bet,
    unsigned short* __restrict__ o)
{
    const int lane = threadIdx.x & 63;
    const int wv   = threadIdx.x >> 6;
    const size_t row = (size_t)blockIdx.x * 4 + wv;
    const float* p0 = x0 + row * K_DIM;
    const float* p1 = x1 + row * K_DIM;

    float v[16];
    #pragma unroll
    for (int i = 0; i < 4; ++i) {
        float4 a = *(const float4*)(p0 + i * 256 + lane * 4);
        float4 b = *(const float4*)(p1 + i * 256 + lane * 4);
        v[4*i+0] = a.x + b.x; v[4*i+1] = a.y + b.y;
        v[4*i+2] = a.z + b.z; v[4*i+3] = a.w + b.w;
    }

    float s = 0.f, sq = 0.f;
    #pragma unroll
    for (int i = 0; i < 16; ++i) { s += v[i]; sq += v[i] * v[i]; }
    #pragma unroll
    for (int m = 32; m >= 1; m >>= 1) {
        s  += __shfl_xor(s,  m);
        sq += __shfl_xor(sq, m);
    }
    const float mean = s * (1.0f / 1024.0f);
    float var = sq * (1.0f / 1024.0f) - mean * mean;
    var = fmaxf(var, 0.0f);
    const float rstd = rsqrtf(var + 1e-5f);

    unsigned short* po = o + row * K_DIM;
    #pragma unroll
    for (int i = 0; i < 4; ++i) {
        float4 g  = *(const float4*)(gam + i * 256 + lane * 4);
        float4 be = *(const float4*)(bet + i * 256 + lane * 4);
        float y0 = (v[4*i+0] - mean) * rstd * g.x + be.x;
        float y1 = (v[4*i+1] - mean) * rstd * g.y + be.y;
        float y2 = (v[4*i+2] - mean) * rstd * g.z + be.z;
        float y3 = (v[4*i+3] - mean) * rstd * g.w + be.w;
        uint2 r;
        r.x = pack2_bf16(y0, y1);
        r.y = pack2_bf16(y2, y3);
        *(uint2*)(po + i * 256 + lane * 4) = r;
    }
}

// ---------------- W fp32 -> bf16 ----------------
__global__ __launch_bounds__(256) void w_to_bf16(
    const float* __restrict__ w, unsigned short* __restrict__ o)
{
    const size_t i = ((size_t)blockIdx.x * 256 + threadIdx.x) * 4;
    float4 v = *(const float4*)(w + i);
    uint2 r;
    r.x = pack2_bf16(v.x, v.y);
    r.y = pack2_bf16(v.z, v.w);
    *(uint2*)(o + i) = r;
}

// ---------------- GEMM: C[M,N] = gelu(A[M,K] @ B[N,K]^T + bias) ----------------
// 128x128 tile, BK=32, 4 waves each 64x64 via 2x2 of mfma_f32_32x32x16_bf16.
// Staging uses ADD-mod-4 seg swizzle (phys seg = (logical + row) & 3) to keep
// the h=lane>>5 fragment reads bank-balanced; swizzle applied to the GLOBAL
// source so the global_load_lds LDS dest stays linear (wave-uniform + lane*16).
__global__ __launch_bounds__(256) void gemm_bias_gelu(
    const unsigned short* __restrict__ A,    // xn [M,K] bf16
    const unsigned short* __restrict__ B,    // W  [N,K] bf16
    const float* __restrict__ bias,          // [N] fp32
    float* __restrict__ C)                   // [M,N] fp32
{
    __shared__ __align__(16) unsigned short At[128 * 32];
    __shared__ __align__(16) unsigned short Bt[128 * 32];

    const int t  = threadIdx.x;
    const int bn = blockIdx.x;   // 0..31
    const int bm = blockIdx.y;   // 0..97
    const int m0 = bm * 128, n0 = bn * 128;

    // staging: thread t fills LDS slot t (row t>>2, phys seg t&3); global
    // logical seg = (phys - row) & 3.
    const int srow = t >> 2;
    const int gseg = ((t & 3) - srow) & 3;
    const unsigned short* ag0 = A + (size_t)(m0 + srow) * K_DIM + gseg * 8;
    const unsigned short* ag1 = A + (size_t)(m0 + srow + 64) * K_DIM + gseg * 8;
    const unsigned short* bg0 = B + (size_t)(n0 + srow) * K_DIM + gseg * 8;
    const unsigned short* bg1 = B + (size_t)(n0 + srow + 64) * K_DIM + gseg * 8;
    unsigned short* al0 = &At[t * 8];
    unsigned short* al1 = &At[(t + 256) * 8];
    unsigned short* bl0 = &Bt[t * 8];
    unsigned short* bl1 = &Bt[(t + 256) * 8];

    const int lane = t & 63;
    const int w    = t >> 6;
    const int wm   = (w >> 1) * 64;   // wave m-offset in tile
    const int wn   = (w & 1) * 64;    // wave n-offset in tile
    const int ml   = lane & 31;
    const int h    = lane >> 5;

    f32x16 acc[2][2] = {};

    for (int kb = 0; kb < K_DIM / 32; ++kb) {
        __syncthreads();
        async_load16(ag0, al0);
        async_load16(ag1, al1);
        async_load16(bg0, bl0);
        async_load16(bg1, bl1);
        ag0 += 32; ag1 += 32; bg0 += 32; bg1 += 32;
        __syncthreads();

        // fragments: operand [dim=lane&31][k=h*8+j], k-half kk -> logical seg kk*2+h
        bf16x8 af[2][2], bfr[2][2];
        #pragma unroll
        for (int i = 0; i < 2; ++i)
            #pragma unroll
            for (int kk = 0; kk < 2; ++kk) {
                const int ra = wm + i * 32 + ml;
                const int rb = wn + i * 32 + ml;
                af[i][kk]  = *(const bf16x8*)&At[ra * 32 + (((kk * 2 + h + ra) & 3) * 8)];
                bfr[i][kk] = *(const bf16x8*)&Bt[rb * 32 + (((kk * 2 + h + rb) & 3) * 8)];
            }

        #pragma unroll
        for (int kk = 0; kk < 2; ++kk)
            #pragma unroll
            for (int i = 0; i < 2; ++i)
                #pragma unroll
                for (int j = 0; j < 2; ++j)
                    acc[i][j] = __builtin_amdgcn_mfma_f32_32x32x16_bf16(
                        af[i][kk], bfr[j][kk], acc[i][j], 0, 0, 0);
    }

    // epilogue: C/D layout col=lane&31, row=(reg&3)+8*(reg>>2)+4*h
    #pragma unroll
    for (int j = 0; j < 2; ++j) {
        const int n = n0 + wn + j * 32 + ml;
        const float bj = bias[n];
        #pragma unroll
        for (int i = 0; i < 2; ++i) {
            const int mbase = m0 + wm + i * 32 + 4 * h;
            #pragma unroll
            for (int reg = 0; reg < 16; ++reg) {
                const int m = mbase + (reg & 3) + 8 * (reg >> 2);
                C[(size_t)m * N_DIM + n] = gelu_fast(acc[i][j][reg] + bj);
            }
        }
    }
}

extern "C" void kernel_launch(void* const* d_in, const int* in_sizes, int n_in,
                              void* d_out, int out_size, void* d_ws, size_t ws_size,
                              hipStream_t stream) {
    const float* x556 = (const float*)d_in[0];
    const float* x570 = (const float*)d_in[1];
    const float* gam  = (const float*)d_in[2];
    const float* bet  = (const float*)d_in[3];
    const float* Wlin = (const float*)d_in[4];
    const float* blin = (const float*)d_in[5];
    float* out = (float*)d_out;

    unsigned short* xn = (unsigned short*)d_ws;            // 25.69 MB
    unsigned short* wb = xn + (size_t)M_DIM * K_DIM;       // 8.39 MB

    ln_fused<<<M_DIM / 4, 256, 0, stream>>>(x556, x570, gam, bet, xn);
    w_to_bf16<<<(N_DIM * K_DIM / 4) / 256, 256, 0, stream>>>(Wlin, wb);
    gemm_bias_gelu<<<dim3(N_DIM / 128, M_DIM / 128), 256, 0, stream>>>(xn, wb, blin, out);
}